// Round 1
// baseline (557.910 us; speedup 1.0000x reference)
//
#include <hip/hip_runtime.h>
#include <hip/hip_bf16.h>

typedef __bf16 bf16_t;
typedef __bf16 bf16x8 __attribute__((ext_vector_type(8)));
typedef __bf16 bf16x4 __attribute__((ext_vector_type(4)));
typedef float f32x4 __attribute__((ext_vector_type(4)));
typedef unsigned short u16;

#define NROWS 16384
#define KDIM  512
#define HID   256
#define ODIM  128

__device__ __forceinline__ f32x4 mfma16(bf16x8 a, bf16x8 b, f32x4 c) {
  return __builtin_amdgcn_mfma_f32_16x16x32_bf16(a, b, c, 0, 0, 0);
}

// ---------------------------------------------------------------------------
// prep: W1 [512][256] fp32 -> W1T [256][512] bf16 ; W2 [256][128] -> W2T [128][256]
// ---------------------------------------------------------------------------
__global__ __launch_bounds__(256) void prep_w(const float* __restrict__ W1,
                                              const float* __restrict__ W2,
                                              bf16_t* __restrict__ W1T,
                                              bf16_t* __restrict__ W2T) {
  int t = blockIdx.x * 256 + threadIdx.x;
  int stride = gridDim.x * 256;
  for (int e = t; e < HID * KDIM; e += stride) {
    int n = e >> 9, k = e & 511;
    W1T[e] = (bf16_t)W1[k * HID + n];
  }
  for (int e = t; e < ODIM * HID; e += stride) {
    int n = e >> 8, k = e & 255;
    W2T[e] = (bf16_t)W2[k * ODIM + n];
  }
}

// ---------------------------------------------------------------------------
// gemm1: h1 = LeakyReLU(x @ W1 + b1), bf16 out [16384][256]
// block 256 thr (4 waves), tile M=128 N=64, K-chunks of 32
// ---------------------------------------------------------------------------
__global__ __launch_bounds__(256) void gemm1(const float* __restrict__ x,
                                             const bf16_t* __restrict__ W1T,
                                             const float* __restrict__ b1,
                                             bf16_t* __restrict__ h1) {
  __shared__ u16 As[128 * 40];  // [m][k] stride 40 shorts
  __shared__ u16 Bs[64 * 40];   // [n][k]
  int tid = threadIdx.x;
  int lane = tid & 63, w = tid >> 6;
  int r = lane & 15, q = lane >> 4;
  int wm = w & 1, wn = w >> 1;
  int mbase = blockIdx.x * 128, nbase = blockIdx.y * 64;

  f32x4 acc[4][2];
#pragma unroll
  for (int ms = 0; ms < 4; ms++)
#pragma unroll
    for (int ns = 0; ns < 2; ns++) acc[ms][ns] = (f32x4){0.f, 0.f, 0.f, 0.f};

  for (int kb = 0; kb < KDIM; kb += 32) {
    // stage A (convert fp32 -> bf16): 128x32
#pragma unroll
    for (int i = 0; i < 2; i++) {
      int g = tid + 256 * i;
      int rr = g >> 2, c = (g & 3) * 8;
      const float* src = x + (mbase + rr) * KDIM + kb + c;
      f32x4 u0 = *(const f32x4*)src;
      f32x4 u1 = *(const f32x4*)(src + 4);
      bf16x8 pk;
      pk[0] = (bf16_t)u0[0]; pk[1] = (bf16_t)u0[1];
      pk[2] = (bf16_t)u0[2]; pk[3] = (bf16_t)u0[3];
      pk[4] = (bf16_t)u1[0]; pk[5] = (bf16_t)u1[1];
      pk[6] = (bf16_t)u1[2]; pk[7] = (bf16_t)u1[3];
      *(bf16x8*)&As[rr * 40 + c] = pk;
    }
    {
      int rr = tid >> 2, c = (tid & 3) * 8;
      *(bf16x8*)&Bs[rr * 40 + c] =
          *(const bf16x8*)(W1T + (nbase + rr) * KDIM + kb + c);
    }
    __syncthreads();
    bf16x8 af[4], bfr[2];
#pragma unroll
    for (int ms = 0; ms < 4; ms++)
      af[ms] = *(bf16x8*)&As[(wm * 64 + ms * 16 + r) * 40 + q * 8];
#pragma unroll
    for (int ns = 0; ns < 2; ns++)
      bfr[ns] = *(bf16x8*)&Bs[(wn * 32 + ns * 16 + r) * 40 + q * 8];
#pragma unroll
    for (int ms = 0; ms < 4; ms++)
#pragma unroll
      for (int ns = 0; ns < 2; ns++)
        acc[ms][ns] = mfma16(af[ms], bfr[ns], acc[ms][ns]);
    __syncthreads();
  }
  // epilogue: bias + LeakyReLU -> bf16
#pragma unroll
  for (int ns = 0; ns < 2; ns++) {
    int col = nbase + wn * 32 + ns * 16 + r;
    float bias = b1[col];
#pragma unroll
    for (int ms = 0; ms < 4; ms++) {
      int row0 = mbase + wm * 64 + ms * 16 + q * 4;
#pragma unroll
      for (int reg = 0; reg < 4; reg++) {
        float v = acc[ms][ns][reg] + bias;
        v = v >= 0.f ? v : 0.01f * v;
        h1[(row0 + reg) * HID + col] = (bf16_t)v;
      }
    }
  }
}

// ---------------------------------------------------------------------------
// gemm2: h = h1 @ W2 + b2 -> hf fp32, hb bf16, hT bf16 transposed [128][16384]
// ---------------------------------------------------------------------------
__global__ __launch_bounds__(256) void gemm2(const bf16_t* __restrict__ h1,
                                             const bf16_t* __restrict__ W2T,
                                             const float* __restrict__ b2,
                                             float* __restrict__ hf,
                                             bf16_t* __restrict__ hb,
                                             bf16_t* __restrict__ hT) {
  __shared__ u16 As[128 * 40];
  __shared__ u16 Bs[64 * 40];
  int tid = threadIdx.x;
  int lane = tid & 63, w = tid >> 6;
  int r = lane & 15, q = lane >> 4;
  int wm = w & 1, wn = w >> 1;
  int mbase = blockIdx.x * 128, nbase = blockIdx.y * 64;

  f32x4 acc[4][2];
#pragma unroll
  for (int ms = 0; ms < 4; ms++)
#pragma unroll
    for (int ns = 0; ns < 2; ns++) acc[ms][ns] = (f32x4){0.f, 0.f, 0.f, 0.f};

  for (int kb = 0; kb < HID; kb += 32) {
#pragma unroll
    for (int i = 0; i < 2; i++) {
      int g = tid + 256 * i;
      int rr = g >> 2, c = (g & 3) * 8;
      *(bf16x8*)&As[rr * 40 + c] =
          *(const bf16x8*)(h1 + (mbase + rr) * HID + kb + c);
    }
    {
      int rr = tid >> 2, c = (tid & 3) * 8;
      *(bf16x8*)&Bs[rr * 40 + c] =
          *(const bf16x8*)(W2T + (nbase + rr) * HID + kb + c);
    }
    __syncthreads();
    bf16x8 af[4], bfr[2];
#pragma unroll
    for (int ms = 0; ms < 4; ms++)
      af[ms] = *(bf16x8*)&As[(wm * 64 + ms * 16 + r) * 40 + q * 8];
#pragma unroll
    for (int ns = 0; ns < 2; ns++)
      bfr[ns] = *(bf16x8*)&Bs[(wn * 32 + ns * 16 + r) * 40 + q * 8];
#pragma unroll
    for (int ms = 0; ms < 4; ms++)
#pragma unroll
      for (int ns = 0; ns < 2; ns++)
        acc[ms][ns] = mfma16(af[ms], bfr[ns], acc[ms][ns]);
    __syncthreads();
  }
#pragma unroll
  for (int ns = 0; ns < 2; ns++) {
    int col = nbase + wn * 32 + ns * 16 + r;
    float bias = b2[col];
#pragma unroll
    for (int ms = 0; ms < 4; ms++) {
      int row0 = mbase + wm * 64 + ms * 16 + q * 4;
      bf16x4 pk;
#pragma unroll
      for (int reg = 0; reg < 4; reg++) {
        float v = acc[ms][ns][reg] + bias;
        hf[(row0 + reg) * ODIM + col] = v;
        hb[(row0 + reg) * ODIM + col] = (bf16_t)v;
        pk[reg] = (bf16_t)v;
      }
      *(bf16x4*)(hT + col * NROWS + row0) = pk;  // 4 consecutive rows, 8B store
    }
  }
}

// ---------------------------------------------------------------------------
// flash: out = log_softmax(alpha * softmax(mask(h h^T)) h + beta * h)
// 256 blocks x 256 thr. Wave w: q-half (w&1)*32 rows, k-half (w>>1)*8192.
// Transposed orientation: S^T = K_chunk . Q^T ; O^T = K_chunk^T . P^T
// ---------------------------------------------------------------------------
__global__ __launch_bounds__(256, 1) void flash(const bf16_t* __restrict__ hb,
                                                const bf16_t* __restrict__ hT,
                                                const float* __restrict__ hf,
                                                const float* __restrict__ alpha_p,
                                                const float* __restrict__ beta_p,
                                                float* __restrict__ out) {
  __shared__ __align__(16) char smem[48128];
  u16* Krm = (u16*)smem;              // [2][32][136] row-major chunk [kr][d]
  u16* KTm = (u16*)(smem + 17408);    // [2][128][40]  [d][kr]
  u16* Pm  = (u16*)(smem + 37888);    // [4][32][40]   per-wave P [qr][kr]
  float* Om  = (float*)smem;          // merge: [2][32][132]
  float* MLm = (float*)(smem + 33792);// merge: [2][32][2] (m,l)

  int tid = threadIdx.x;
  int lane = tid & 63, w = tid >> 6;
  int r = lane & 15, q = lane >> 4;
  int kh = w >> 1;   // which k-half this wave computes
  int qh = w & 1;    // which 32-row q-group
  int qbase = blockIdx.x * 64 + qh * 32;

  // Q fragments, resident in registers: [qt][kk]
  bf16x8 qf[2][4];
#pragma unroll
  for (int qt = 0; qt < 2; qt++) {
    int qrow = qbase + qt * 16 + r;
#pragma unroll
    for (int kk = 0; kk < 4; kk++)
      qf[qt][kk] = *(const bf16x8*)(hb + qrow * ODIM + kk * 32 + q * 8);
  }

  f32x4 oa[8][2];
#pragma unroll
  for (int m8 = 0; m8 < 8; m8++)
#pragma unroll
    for (int qt = 0; qt < 2; qt++) oa[m8][qt] = (f32x4){0.f, 0.f, 0.f, 0.f};
  float m_run[2] = {0.f, 0.f}, l_run[2] = {0.f, 0.f};

  for (int kb = 0; kb < 8192; kb += 32) {
    // ---- stage both k-halves (all 256 threads) ----
#pragma unroll
    for (int hh = 0; hh < 2; hh++) {
      int kg = hh * 8192 + kb;
#pragma unroll
      for (int i = 0; i < 2; i++) {
        int g = tid + 256 * i;
        int rr = g >> 4, c = (g & 15) * 8;
        *(bf16x8*)&Krm[hh * 4352 + rr * 136 + c] =
            *(const bf16x8*)(hb + (kg + rr) * ODIM + c);
      }
#pragma unroll
      for (int i = 0; i < 2; i++) {
        int g = tid + 256 * i;
        int d = g >> 2, c = (g & 3) * 8;
        *(bf16x8*)&KTm[hh * 5120 + d * 40 + c] =
            *(const bf16x8*)(hT + d * NROWS + kg + c);
      }
    }
    __syncthreads();

    // ---- S^T = K_chunk . Q^T  (D[kr][qr]) ----
    f32x4 s[2][2];
#pragma unroll
    for (int mt = 0; mt < 2; mt++)
#pragma unroll
      for (int qt = 0; qt < 2; qt++) s[mt][qt] = (f32x4){0.f, 0.f, 0.f, 0.f};
#pragma unroll
    for (int mt = 0; mt < 2; mt++) {
#pragma unroll
      for (int kk = 0; kk < 4; kk++) {
        bf16x8 af =
            *(bf16x8*)&Krm[kh * 4352 + (mt * 16 + r) * 136 + kk * 32 + q * 8];
        s[mt][0] = mfma16(af, qf[0][kk], s[mt][0]);
        s[mt][1] = mfma16(af, qf[1][kk], s[mt][1]);
      }
    }

    // ---- masked online softmax (stats per q-row = lane&15) ----
    float sc[2];
#pragma unroll
    for (int qt = 0; qt < 2; qt++) {
      float mx = m_run[qt];
#pragma unroll
      for (int mt = 0; mt < 2; mt++)
#pragma unroll
        for (int reg = 0; reg < 4; reg++) {
          float v = s[mt][qt][reg];
          if (v > 0.f) mx = fmaxf(mx, v);
        }
      mx = fmaxf(mx, __shfl_xor(mx, 16, 64));
      mx = fmaxf(mx, __shfl_xor(mx, 32, 64));
      sc[qt] = __expf(m_run[qt] - mx);
      m_run[qt] = mx;
      float rs = 0.f;
      bf16x4 pk[2];
#pragma unroll
      for (int mt = 0; mt < 2; mt++)
#pragma unroll
        for (int reg = 0; reg < 4; reg++) {
          float v = s[mt][qt][reg];
          float p = v > 0.f ? __expf(v - mx) : 0.f;
          rs += p;
          pk[mt][reg] = (bf16_t)p;
        }
      rs += __shfl_xor(rs, 16, 64);
      rs += __shfl_xor(rs, 32, 64);
      l_run[qt] = l_run[qt] * sc[qt] + rs;
#pragma unroll
      for (int mt = 0; mt < 2; mt++)
        *(bf16x4*)&Pm[w * 1280 + (qt * 16 + r) * 40 + mt * 16 + q * 4] = pk[mt];
    }

    // ---- rescale O, then O^T += K^T . P^T ----
#pragma unroll
    for (int m8 = 0; m8 < 8; m8++)
#pragma unroll
      for (int qt = 0; qt < 2; qt++)
#pragma unroll
        for (int reg = 0; reg < 4; reg++) oa[m8][qt][reg] *= sc[qt];

    bf16x8 pf0 = *(bf16x8*)&Pm[w * 1280 + r * 40 + q * 8];
    bf16x8 pf1 = *(bf16x8*)&Pm[w * 1280 + (16 + r) * 40 + q * 8];
#pragma unroll
    for (int m8 = 0; m8 < 8; m8++) {
      bf16x8 af = *(bf16x8*)&KTm[kh * 5120 + (m8 * 16 + r) * 40 + q * 8];
      oa[m8][0] = mfma16(af, pf0, oa[m8][0]);
      oa[m8][1] = mfma16(af, pf1, oa[m8][1]);
    }
    __syncthreads();
  }

  // ---- merge k-halves through LDS (aliases staging buffers; loop is done) ----
  if (kh == 1) {
#pragma unroll
    for (int qt = 0; qt < 2; qt++)
#pragma unroll
      for (int m8 = 0; m8 < 8; m8++)
        *(f32x4*)&Om[qh * 4224 + (qt * 16 + r) * 132 + m8 * 16 + q * 4] =
            oa[m8][qt];
    if (q == 0) {
#pragma unroll
      for (int qt = 0; qt < 2; qt++) {
        MLm[(qh * 32 + qt * 16 + r) * 2 + 0] = m_run[qt];
        MLm[(qh * 32 + qt * 16 + r) * 2 + 1] = l_run[qt];
      }
    }
  }
  __syncthreads();
  if (kh == 0) {
    float al = alpha_p[0], be = beta_p[0];
#pragma unroll
    for (int qt = 0; qt < 2; qt++) {
      float m2 = MLm[(qh * 32 + qt * 16 + r) * 2 + 0];
      float l2 = MLm[(qh * 32 + qt * 16 + r) * 2 + 1];
      float M = fmaxf(m_run[qt], m2);
      float a1 = __expf(m_run[qt] - M);
      float a2 = __expf(m2 - M);
      float l = l_run[qt] * a1 + l2 * a2;
      float inv = al / l;
      int qrow = qbase + qt * 16 + r;
      float vals[8][4];
      float mx = -1e30f;
#pragma unroll
      for (int m8 = 0; m8 < 8; m8++) {
        f32x4 o2 = *(f32x4*)&Om[qh * 4224 + (qt * 16 + r) * 132 + m8 * 16 + q * 4];
        f32x4 hv = *(const f32x4*)(hf + qrow * ODIM + m8 * 16 + q * 4);
#pragma unroll
        for (int reg = 0; reg < 4; reg++) {
          float ov = oa[m8][qt][reg] * a1 + o2[reg] * a2;
          float v = inv * ov + be * hv[reg];
          vals[m8][reg] = v;
          mx = fmaxf(mx, v);
        }
      }
      mx = fmaxf(mx, __shfl_xor(mx, 16, 64));
      mx = fmaxf(mx, __shfl_xor(mx, 32, 64));
      float se = 0.f;
#pragma unroll
      for (int m8 = 0; m8 < 8; m8++)
#pragma unroll
        for (int reg = 0; reg < 4; reg++) se += __expf(vals[m8][reg] - mx);
      se += __shfl_xor(se, 16, 64);
      se += __shfl_xor(se, 32, 64);
      float lz = mx + __logf(se);
#pragma unroll
      for (int m8 = 0; m8 < 8; m8++) {
        f32x4 st;
#pragma unroll
        for (int reg = 0; reg < 4; reg++) st[reg] = vals[m8][reg] - lz;
        *(f32x4*)(out + qrow * ODIM + m8 * 16 + q * 4) = st;
      }
    }
  }
}

// ---------------------------------------------------------------------------
extern "C" void kernel_launch(void* const* d_in, const int* in_sizes, int n_in,
                              void* d_out, int out_size, void* d_ws,
                              size_t ws_size, hipStream_t stream) {
  const float* x     = (const float*)d_in[0];
  const float* W1    = (const float*)d_in[2];
  const float* b1    = (const float*)d_in[3];
  const float* W2    = (const float*)d_in[4];
  const float* b2    = (const float*)d_in[5];
  const float* alpha = (const float*)d_in[6];
  const float* beta  = (const float*)d_in[7];

  char* ws = (char*)d_ws;
  bf16_t* W1T = (bf16_t*)(ws + 0);         //  256 KB
  bf16_t* W2T = (bf16_t*)(ws + 262144);    //   64 KB
  bf16_t* h1  = (bf16_t*)(ws + 327680);    //    8 MB
  float*  hf  = (float*)(ws + 8716288);    //    8 MB
  bf16_t* hbf = (bf16_t*)(ws + 17104896);  //    4 MB
  bf16_t* hT  = (bf16_t*)(ws + 21299200);  //    4 MB  (total ~24.3 MB)
  float* outp = (float*)d_out;

  prep_w<<<256, 256, 0, stream>>>(W1, W2, W1T, W2T);
  gemm1<<<dim3(128, 4), 256, 0, stream>>>(x, W1T, b1, h1);
  gemm2<<<dim3(128, 2), 256, 0, stream>>>(h1, W2T, b2, hf, hbf, hT);
  flash<<<256, 256, 0, stream>>>(hbf, hT, hf, alpha, beta, outp);
}

// Round 2
// 470.930 us; speedup vs baseline: 1.1847x; 1.1847x over previous
//
#include <hip/hip_runtime.h>
#include <hip/hip_bf16.h>

typedef __bf16 bf16_t;
typedef __bf16 bf16x8 __attribute__((ext_vector_type(8)));
typedef __bf16 bf16x4 __attribute__((ext_vector_type(4)));
typedef __bf16 bf16x2 __attribute__((ext_vector_type(2)));
typedef float f32x4 __attribute__((ext_vector_type(4)));
typedef float f32x2 __attribute__((ext_vector_type(2)));
typedef unsigned short u16;

#define NROWS 16384
#define KDIM  512
#define HID   256
#define ODIM  128

__device__ __forceinline__ f32x4 mfma16(bf16x8 a, bf16x8 b, f32x4 c) {
  return __builtin_amdgcn_mfma_f32_16x16x32_bf16(a, b, c, 0, 0, 0);
}

// ---------------------------------------------------------------------------
// prep: W1 [512][256] fp32 -> W1T [256][512] bf16 ; W2 [256][128] -> W2T [128][256]
// ---------------------------------------------------------------------------
__global__ __launch_bounds__(256) void prep_w(const float* __restrict__ W1,
                                              const float* __restrict__ W2,
                                              bf16_t* __restrict__ W1T,
                                              bf16_t* __restrict__ W2T) {
  int t = blockIdx.x * 256 + threadIdx.x;
  int stride = gridDim.x * 256;
  for (int e = t; e < HID * KDIM; e += stride) {
    int n = e >> 9, k = e & 511;
    W1T[e] = (bf16_t)W1[k * HID + n];
  }
  for (int e = t; e < ODIM * HID; e += stride) {
    int n = e >> 8, k = e & 255;
    W2T[e] = (bf16_t)W2[k * ODIM + n];
  }
}

// ---------------------------------------------------------------------------
// gemm1: h1 = LeakyReLU(x @ W1 + b1), bf16 out [16384][256]
// ---------------------------------------------------------------------------
__global__ __launch_bounds__(256) void gemm1(const float* __restrict__ x,
                                             const bf16_t* __restrict__ W1T,
                                             const float* __restrict__ b1,
                                             bf16_t* __restrict__ h1) {
  __shared__ u16 As[128 * 40];
  __shared__ u16 Bs[64 * 40];
  int tid = threadIdx.x;
  int lane = tid & 63, w = tid >> 6;
  int r = lane & 15, q = lane >> 4;
  int wm = w & 1, wn = w >> 1;
  int mbase = blockIdx.x * 128, nbase = blockIdx.y * 64;

  f32x4 acc[4][2];
#pragma unroll
  for (int ms = 0; ms < 4; ms++)
#pragma unroll
    for (int ns = 0; ns < 2; ns++) acc[ms][ns] = (f32x4){0.f, 0.f, 0.f, 0.f};

  for (int kb = 0; kb < KDIM; kb += 32) {
#pragma unroll
    for (int i = 0; i < 2; i++) {
      int g = tid + 256 * i;
      int rr = g >> 2, c = (g & 3) * 8;
      const float* src = x + (mbase + rr) * KDIM + kb + c;
      f32x4 u0 = *(const f32x4*)src;
      f32x4 u1 = *(const f32x4*)(src + 4);
      bf16x8 pk;
      pk[0] = (bf16_t)u0[0]; pk[1] = (bf16_t)u0[1];
      pk[2] = (bf16_t)u0[2]; pk[3] = (bf16_t)u0[3];
      pk[4] = (bf16_t)u1[0]; pk[5] = (bf16_t)u1[1];
      pk[6] = (bf16_t)u1[2]; pk[7] = (bf16_t)u1[3];
      *(bf16x8*)&As[rr * 40 + c] = pk;
    }
    {
      int rr = tid >> 2, c = (tid & 3) * 8;
      *(bf16x8*)&Bs[rr * 40 + c] =
          *(const bf16x8*)(W1T + (nbase + rr) * KDIM + kb + c);
    }
    __syncthreads();
    bf16x8 af[4], bfr[2];
#pragma unroll
    for (int ms = 0; ms < 4; ms++)
      af[ms] = *(bf16x8*)&As[(wm * 64 + ms * 16 + r) * 40 + q * 8];
#pragma unroll
    for (int ns = 0; ns < 2; ns++)
      bfr[ns] = *(bf16x8*)&Bs[(wn * 32 + ns * 16 + r) * 40 + q * 8];
#pragma unroll
    for (int ms = 0; ms < 4; ms++)
#pragma unroll
      for (int ns = 0; ns < 2; ns++)
        acc[ms][ns] = mfma16(af[ms], bfr[ns], acc[ms][ns]);
    __syncthreads();
  }
#pragma unroll
  for (int ns = 0; ns < 2; ns++) {
    int col = nbase + wn * 32 + ns * 16 + r;
    float bias = b1[col];
#pragma unroll
    for (int ms = 0; ms < 4; ms++) {
      int row0 = mbase + wm * 64 + ms * 16 + q * 4;
#pragma unroll
      for (int reg = 0; reg < 4; reg++) {
        float v = acc[ms][ns][reg] + bias;
        v = v >= 0.f ? v : 0.01f * v;
        h1[(row0 + reg) * HID + col] = (bf16_t)v;
      }
    }
  }
}

// ---------------------------------------------------------------------------
// gemm2: h = h1 @ W2 + b2 -> hf fp32, hb bf16, hT bf16 transposed [128][16384]
// ---------------------------------------------------------------------------
__global__ __launch_bounds__(256) void gemm2(const bf16_t* __restrict__ h1,
                                             const bf16_t* __restrict__ W2T,
                                             const float* __restrict__ b2,
                                             float* __restrict__ hf,
                                             bf16_t* __restrict__ hb,
                                             bf16_t* __restrict__ hT) {
  __shared__ u16 As[128 * 40];
  __shared__ u16 Bs[64 * 40];
  int tid = threadIdx.x;
  int lane = tid & 63, w = tid >> 6;
  int r = lane & 15, q = lane >> 4;
  int wm = w & 1, wn = w >> 1;
  int mbase = blockIdx.x * 128, nbase = blockIdx.y * 64;

  f32x4 acc[4][2];
#pragma unroll
  for (int ms = 0; ms < 4; ms++)
#pragma unroll
    for (int ns = 0; ns < 2; ns++) acc[ms][ns] = (f32x4){0.f, 0.f, 0.f, 0.f};

  for (int kb = 0; kb < HID; kb += 32) {
#pragma unroll
    for (int i = 0; i < 2; i++) {
      int g = tid + 256 * i;
      int rr = g >> 2, c = (g & 3) * 8;
      *(bf16x8*)&As[rr * 40 + c] =
          *(const bf16x8*)(h1 + (mbase + rr) * HID + kb + c);
    }
    {
      int rr = tid >> 2, c = (tid & 3) * 8;
      *(bf16x8*)&Bs[rr * 40 + c] =
          *(const bf16x8*)(W2T + (nbase + rr) * HID + kb + c);
    }
    __syncthreads();
    bf16x8 af[4], bfr[2];
#pragma unroll
    for (int ms = 0; ms < 4; ms++)
      af[ms] = *(bf16x8*)&As[(wm * 64 + ms * 16 + r) * 40 + q * 8];
#pragma unroll
    for (int ns = 0; ns < 2; ns++)
      bfr[ns] = *(bf16x8*)&Bs[(wn * 32 + ns * 16 + r) * 40 + q * 8];
#pragma unroll
    for (int ms = 0; ms < 4; ms++)
#pragma unroll
      for (int ns = 0; ns < 2; ns++)
        acc[ms][ns] = mfma16(af[ms], bfr[ns], acc[ms][ns]);
    __syncthreads();
  }
#pragma unroll
  for (int ns = 0; ns < 2; ns++) {
    int col = nbase + wn * 32 + ns * 16 + r;
    float bias = b2[col];
#pragma unroll
    for (int ms = 0; ms < 4; ms++) {
      int row0 = mbase + wm * 64 + ms * 16 + q * 4;
      bf16x4 pk;
#pragma unroll
      for (int reg = 0; reg < 4; reg++) {
        float v = acc[ms][ns][reg] + bias;
        hf[(row0 + reg) * ODIM + col] = v;
        hb[(row0 + reg) * ODIM + col] = (bf16_t)v;
        pk[reg] = (bf16_t)v;
      }
      *(bf16x4*)(hT + col * NROWS + row0) = pk;
    }
  }
}

// ---------------------------------------------------------------------------
// flash (split-K): grid = 128 q-tiles x KS k-splits. Block = 4 waves, each
// wave owns 32 q-rows; all 4 waves share one staged 32-k chunk.
// Writes per-split partials: O (bf16), m, l.
// ---------------------------------------------------------------------------
__global__ __launch_bounds__(256, 4) void flash(const bf16_t* __restrict__ hb,
                                                const bf16_t* __restrict__ hT,
                                                bf16_t* __restrict__ Op,
                                                float* __restrict__ Ml,
                                                int k_range) {
  __shared__ u16 Krm[32 * 136];   // [kr][d]  stride 136 shorts (17x16B, odd)
  __shared__ u16 KTm[128 * 40];   // [d][kr]  stride 40 shorts (5x16B, odd)
  __shared__ u16 Pm[4 * 32 * 40]; // per-wave P [qr][kr]

  int tid = threadIdx.x;
  int lane = tid & 63, w = tid >> 6;
  int r = lane & 15, q = lane >> 4;
  int ksplit = blockIdx.x >> 7;
  int qtile = blockIdx.x & 127;
  int qbase = qtile * 128 + w * 32;
  int kbase = ksplit * k_range;

  // Q fragments resident in registers
  bf16x8 qf[2][4];
#pragma unroll
  for (int qt = 0; qt < 2; qt++) {
    int qrow = qbase + qt * 16 + r;
#pragma unroll
    for (int kk = 0; kk < 4; kk++)
      qf[qt][kk] = *(const bf16x8*)(hb + qrow * ODIM + kk * 32 + q * 8);
  }

  f32x4 oa[8][2];
#pragma unroll
  for (int m8 = 0; m8 < 8; m8++)
#pragma unroll
    for (int qt = 0; qt < 2; qt++) oa[m8][qt] = (f32x4){0.f, 0.f, 0.f, 0.f};
  float m_run[2] = {0.f, 0.f}, l_run[2] = {0.f, 0.f};

  for (int kb = kbase; kb < kbase + k_range; kb += 32) {
    // ---- stage this block's 32-k chunk (row-major + transposed) ----
#pragma unroll
    for (int i = 0; i < 2; i++) {
      int g = tid + 256 * i;
      int rr = g >> 4, c = (g & 15) * 8;
      *(bf16x8*)&Krm[rr * 136 + c] = *(const bf16x8*)(hb + (kb + rr) * ODIM + c);
    }
#pragma unroll
    for (int i = 0; i < 2; i++) {
      int g = tid + 256 * i;
      int d = g >> 2, c = (g & 3) * 8;
      *(bf16x8*)&KTm[d * 40 + c] = *(const bf16x8*)(hT + d * NROWS + kb + c);
    }
    __syncthreads();

    // ---- S^T = K_chunk . Q^T ----
    f32x4 s[2][2];
#pragma unroll
    for (int mt = 0; mt < 2; mt++)
#pragma unroll
      for (int qt = 0; qt < 2; qt++) s[mt][qt] = (f32x4){0.f, 0.f, 0.f, 0.f};
#pragma unroll
    for (int mt = 0; mt < 2; mt++) {
#pragma unroll
      for (int kk = 0; kk < 4; kk++) {
        bf16x8 af = *(bf16x8*)&Krm[(mt * 16 + r) * 136 + kk * 32 + q * 8];
        s[mt][0] = mfma16(af, qf[0][kk], s[mt][0]);
        s[mt][1] = mfma16(af, qf[1][kk], s[mt][1]);
      }
    }

    // ---- masked online softmax (stats per q-row = lane&15) ----
    float sc[2];
#pragma unroll
    for (int qt = 0; qt < 2; qt++) {
      float mx = m_run[qt];
#pragma unroll
      for (int mt = 0; mt < 2; mt++)
#pragma unroll
        for (int reg = 0; reg < 4; reg++) {
          float v = s[mt][qt][reg];
          mx = v > 0.f ? fmaxf(mx, v) : mx;
        }
      mx = fmaxf(mx, __shfl_xor(mx, 16, 64));
      mx = fmaxf(mx, __shfl_xor(mx, 32, 64));
      sc[qt] = __expf(m_run[qt] - mx);
      m_run[qt] = mx;
      float rs = 0.f;
      bf16x4 pk[2];
#pragma unroll
      for (int mt = 0; mt < 2; mt++)
#pragma unroll
        for (int reg = 0; reg < 4; reg++) {
          float v = s[mt][qt][reg];
          float p = v > 0.f ? __expf(v - mx) : 0.f;
          rs += p;
          pk[mt][reg] = (bf16_t)p;
        }
      rs += __shfl_xor(rs, 16, 64);
      rs += __shfl_xor(rs, 32, 64);
      l_run[qt] = l_run[qt] * sc[qt] + rs;
#pragma unroll
      for (int mt = 0; mt < 2; mt++)
        *(bf16x4*)&Pm[w * 1280 + (qt * 16 + r) * 40 + mt * 16 + q * 4] = pk[mt];
    }

    // ---- rescale O, then O^T += K^T . P^T ----
#pragma unroll
    for (int m8 = 0; m8 < 8; m8++)
#pragma unroll
      for (int qt = 0; qt < 2; qt++)
#pragma unroll
        for (int reg = 0; reg < 4; reg++) oa[m8][qt][reg] *= sc[qt];

    bf16x8 pf0 = *(bf16x8*)&Pm[w * 1280 + r * 40 + q * 8];
    bf16x8 pf1 = *(bf16x8*)&Pm[w * 1280 + (16 + r) * 40 + q * 8];
#pragma unroll
    for (int m8 = 0; m8 < 8; m8++) {
      bf16x8 af = *(bf16x8*)&KTm[(m8 * 16 + r) * 40 + q * 8];
      oa[m8][0] = mfma16(af, pf0, oa[m8][0]);
      oa[m8][1] = mfma16(af, pf1, oa[m8][1]);
    }
    __syncthreads();
  }

  // ---- write partials: Op[ksplit][row][d] bf16, Ml[ksplit][row][{m,l}] ----
#pragma unroll
  for (int qt = 0; qt < 2; qt++) {
    int row = qbase + qt * 16 + r;
    int prow = ksplit * NROWS + row;
#pragma unroll
    for (int m8 = 0; m8 < 8; m8++) {
      bf16x4 pk;
#pragma unroll
      for (int reg = 0; reg < 4; reg++) pk[reg] = (bf16_t)oa[m8][qt][reg];
      *(bf16x4*)(Op + (size_t)prow * ODIM + m8 * 16 + q * 4) = pk;
    }
    if (q == 0) {
      Ml[prow * 2 + 0] = m_run[qt];
      Ml[prow * 2 + 1] = l_run[qt];
    }
  }
}

// ---------------------------------------------------------------------------
// merge: combine KS partials, apply alpha/beta/hf, log_softmax, write out.
// grid 512 x 256; wave handles 8 rows, lane covers 2 d-columns.
// ---------------------------------------------------------------------------
__global__ __launch_bounds__(256) void merge_ls(const bf16_t* __restrict__ Op,
                                                const float* __restrict__ Ml,
                                                const float* __restrict__ hf,
                                                const float* __restrict__ alpha_p,
                                                const float* __restrict__ beta_p,
                                                float* __restrict__ out, int KS) {
  int tid = threadIdx.x, lane = tid & 63, w = tid >> 6;
  float al = alpha_p[0], be = beta_p[0];
  for (int i = 0; i < 8; i++) {
    int row = blockIdx.x * 32 + w * 8 + i;
    float mk[8], lk[8], ak[8];
    float M = 0.f;
    for (int ksp = 0; ksp < KS; ksp++) {
      mk[ksp] = Ml[(ksp * NROWS + row) * 2 + 0];
      lk[ksp] = Ml[(ksp * NROWS + row) * 2 + 1];
      M = fmaxf(M, mk[ksp]);
    }
    float lt = 0.f;
    for (int ksp = 0; ksp < KS; ksp++) {
      ak[ksp] = __expf(mk[ksp] - M);
      lt += lk[ksp] * ak[ksp];
    }
    float inv = al / lt;
    int d0 = lane * 2;
    float a0 = 0.f, a1 = 0.f;
    for (int ksp = 0; ksp < KS; ksp++) {
      bf16x2 v = *(const bf16x2*)(Op + ((size_t)ksp * NROWS + row) * ODIM + d0);
      a0 += ak[ksp] * (float)v[0];
      a1 += ak[ksp] * (float)v[1];
    }
    f32x2 hv = *(const f32x2*)(hf + (size_t)row * ODIM + d0);
    float v0 = inv * a0 + be * hv[0];
    float v1 = inv * a1 + be * hv[1];
    float mx = fmaxf(v0, v1);
#pragma unroll
    for (int off = 1; off < 64; off <<= 1) mx = fmaxf(mx, __shfl_xor(mx, off, 64));
    float se = __expf(v0 - mx) + __expf(v1 - mx);
#pragma unroll
    for (int off = 1; off < 64; off <<= 1) se += __shfl_xor(se, off, 64);
    float lz = mx + __logf(se);
    f32x2 st = {v0 - lz, v1 - lz};
    *(f32x2*)(out + (size_t)row * ODIM + d0) = st;
  }
}

// ---------------------------------------------------------------------------
extern "C" void kernel_launch(void* const* d_in, const int* in_sizes, int n_in,
                              void* d_out, int out_size, void* d_ws,
                              size_t ws_size, hipStream_t stream) {
  const float* x     = (const float*)d_in[0];
  const float* W1    = (const float*)d_in[2];
  const float* b1    = (const float*)d_in[3];
  const float* W2    = (const float*)d_in[4];
  const float* b2    = (const float*)d_in[5];
  const float* alpha = (const float*)d_in[6];
  const float* beta  = (const float*)d_in[7];

  char* ws = (char*)d_ws;
  bf16_t* W1T = (bf16_t*)(ws + 0);          //  256 KB
  bf16_t* W2T = (bf16_t*)(ws + 262144);     //   64 KB
  bf16_t* h1  = (bf16_t*)(ws + 327680);     //    8 MB
  float*  hf  = (float*)(ws + 8716288);     //    8 MB
  bf16_t* hbf = (bf16_t*)(ws + 17104896);   //    4 MB
  bf16_t* hT  = (bf16_t*)(ws + 21299200);   //    4 MB (ends 25493504)
  float*  Ml  = (float*)(ws + 25493504);    //    1 MB (KS<=8)
  bf16_t* Op  = (bf16_t*)(ws + 26542080);   // KS x 4 MB
  float* outp = (float*)d_out;

  // pick largest split count whose partial buffers fit in ws
  int KS = 1;
  const size_t opbase = 26542080;
  const size_t per_split = (size_t)NROWS * ODIM * 2;
  if (ws_size >= opbase + 8 * per_split) KS = 8;
  else if (ws_size >= opbase + 4 * per_split) KS = 4;
  else if (ws_size >= opbase + 2 * per_split) KS = 2;
  int k_range = NROWS / KS;

  prep_w<<<256, 256, 0, stream>>>(W1, W2, W1T, W2T);
  gemm1<<<dim3(128, 4), 256, 0, stream>>>(x, W1T, b1, h1);
  gemm2<<<dim3(128, 2), 256, 0, stream>>>(h1, W2T, b2, hf, hbf, hT);
  flash<<<128 * KS, 256, 0, stream>>>(hbf, hT, Op, Ml, k_range);
  merge_ls<<<512, 256, 0, stream>>>(Op, Ml, hf, alpha, beta, outp, KS);
}

// Round 3
// 364.290 us; speedup vs baseline: 1.5315x; 1.2927x over previous
//
#include <hip/hip_runtime.h>
#include <hip/hip_bf16.h>

typedef __bf16 bf16_t;
typedef __bf16 bf16x8 __attribute__((ext_vector_type(8)));
typedef __bf16 bf16x4 __attribute__((ext_vector_type(4)));
typedef __bf16 bf16x2 __attribute__((ext_vector_type(2)));
typedef float f32x4 __attribute__((ext_vector_type(4)));
typedef float f32x2 __attribute__((ext_vector_type(2)));
typedef unsigned short u16;

#define NROWS 16384
#define KDIM  512
#define HID   256
#define ODIM  128
#define KS    8

__device__ __forceinline__ f32x4 mfma16(bf16x8 a, bf16x8 b, f32x4 c) {
  return __builtin_amdgcn_mfma_f32_16x16x32_bf16(a, b, c, 0, 0, 0);
}

// async global->LDS DMA, 16B per lane; lds dst must be wave-uniform base (+lane*16)
__device__ __forceinline__ void dma16(const void* g, void* l) {
  __builtin_amdgcn_global_load_lds(
      (const __attribute__((address_space(1))) unsigned int*)g,
      (__attribute__((address_space(3))) unsigned int*)l, 16, 0, 0);
}

// ---------------------------------------------------------------------------
// prep: x fp32 -> xb bf16 ; W1 -> W1T bf16 ; W2 -> W2T bf16
// ---------------------------------------------------------------------------
__global__ __launch_bounds__(256) void prep(const float* __restrict__ x,
                                            const float* __restrict__ W1,
                                            const float* __restrict__ W2,
                                            bf16_t* __restrict__ xb,
                                            bf16_t* __restrict__ W1T,
                                            bf16_t* __restrict__ W2T) {
  int t = blockIdx.x * 256 + threadIdx.x;
  int stride = gridDim.x * 256;
  for (int e = t; e < NROWS * KDIM / 4; e += stride) {
    f32x4 v = *(const f32x4*)(x + (size_t)e * 4);
    bf16x4 pk;
    pk[0] = (bf16_t)v[0]; pk[1] = (bf16_t)v[1];
    pk[2] = (bf16_t)v[2]; pk[3] = (bf16_t)v[3];
    *(bf16x4*)(xb + (size_t)e * 4) = pk;
  }
  for (int e = t; e < HID * KDIM; e += stride) {
    int n = e >> 9, k = e & 511;
    W1T[e] = (bf16_t)W1[k * HID + n];
  }
  for (int e = t; e < ODIM * HID; e += stride) {
    int n = e >> 8, k = e & 255;
    W2T[e] = (bf16_t)W2[k * ODIM + n];
  }
}

// ---------------------------------------------------------------------------
// gemm1: h1 = LeakyReLU(xb @ W1 + b1), bf16 out [16384][256]
// ---------------------------------------------------------------------------
__global__ __launch_bounds__(256) void gemm1(const bf16_t* __restrict__ xb,
                                             const bf16_t* __restrict__ W1T,
                                             const float* __restrict__ b1,
                                             bf16_t* __restrict__ h1) {
  __shared__ u16 As[128 * 40];
  __shared__ u16 Bs[64 * 40];
  int tid = threadIdx.x;
  int lane = tid & 63, w = tid >> 6;
  int r = lane & 15, q = lane >> 4;
  int wm = w & 1, wn = w >> 1;
  int mbase = blockIdx.x * 128, nbase = blockIdx.y * 64;

  f32x4 acc[4][2];
#pragma unroll
  for (int ms = 0; ms < 4; ms++)
#pragma unroll
    for (int ns = 0; ns < 2; ns++) acc[ms][ns] = (f32x4){0.f, 0.f, 0.f, 0.f};

  for (int kb = 0; kb < KDIM; kb += 32) {
#pragma unroll
    for (int i = 0; i < 2; i++) {
      int g = tid + 256 * i;
      int rr = g >> 2, c = (g & 3) * 8;
      *(bf16x8*)&As[rr * 40 + c] =
          *(const bf16x8*)(xb + (size_t)(mbase + rr) * KDIM + kb + c);
    }
    {
      int rr = tid >> 2, c = (tid & 3) * 8;
      *(bf16x8*)&Bs[rr * 40 + c] =
          *(const bf16x8*)(W1T + (size_t)(nbase + rr) * KDIM + kb + c);
    }
    __syncthreads();
    bf16x8 af[4], bfr[2];
#pragma unroll
    for (int ms = 0; ms < 4; ms++)
      af[ms] = *(bf16x8*)&As[(wm * 64 + ms * 16 + r) * 40 + q * 8];
#pragma unroll
    for (int ns = 0; ns < 2; ns++)
      bfr[ns] = *(bf16x8*)&Bs[(wn * 32 + ns * 16 + r) * 40 + q * 8];
#pragma unroll
    for (int ms = 0; ms < 4; ms++)
#pragma unroll
      for (int ns = 0; ns < 2; ns++)
        acc[ms][ns] = mfma16(af[ms], bfr[ns], acc[ms][ns]);
    __syncthreads();
  }
#pragma unroll
  for (int ns = 0; ns < 2; ns++) {
    int col = nbase + wn * 32 + ns * 16 + r;
    float bias = b1[col];
#pragma unroll
    for (int ms = 0; ms < 4; ms++) {
      int row0 = mbase + wm * 64 + ms * 16 + q * 4;
#pragma unroll
      for (int reg = 0; reg < 4; reg++) {
        float v = acc[ms][ns][reg] + bias;
        v = v >= 0.f ? v : 0.01f * v;
        h1[(size_t)(row0 + reg) * HID + col] = (bf16_t)v;
      }
    }
  }
}

// ---------------------------------------------------------------------------
// gemm2: h = h1 @ W2 + b2 -> hb bf16 [16384][128], hT bf16 [128][16384]
// ---------------------------------------------------------------------------
__global__ __launch_bounds__(256) void gemm2(const bf16_t* __restrict__ h1,
                                             const bf16_t* __restrict__ W2T,
                                             const float* __restrict__ b2,
                                             bf16_t* __restrict__ hb,
                                             bf16_t* __restrict__ hT) {
  __shared__ u16 As[128 * 40];
  __shared__ u16 Bs[64 * 40];
  int tid = threadIdx.x;
  int lane = tid & 63, w = tid >> 6;
  int r = lane & 15, q = lane >> 4;
  int wm = w & 1, wn = w >> 1;
  int mbase = blockIdx.x * 128, nbase = blockIdx.y * 64;

  f32x4 acc[4][2];
#pragma unroll
  for (int ms = 0; ms < 4; ms++)
#pragma unroll
    for (int ns = 0; ns < 2; ns++) acc[ms][ns] = (f32x4){0.f, 0.f, 0.f, 0.f};

  for (int kb = 0; kb < HID; kb += 32) {
#pragma unroll
    for (int i = 0; i < 2; i++) {
      int g = tid + 256 * i;
      int rr = g >> 2, c = (g & 3) * 8;
      *(bf16x8*)&As[rr * 40 + c] =
          *(const bf16x8*)(h1 + (size_t)(mbase + rr) * HID + kb + c);
    }
    {
      int rr = tid >> 2, c = (tid & 3) * 8;
      *(bf16x8*)&Bs[rr * 40 + c] =
          *(const bf16x8*)(W2T + (size_t)(nbase + rr) * HID + kb + c);
    }
    __syncthreads();
    bf16x8 af[4], bfr[2];
#pragma unroll
    for (int ms = 0; ms < 4; ms++)
      af[ms] = *(bf16x8*)&As[(wm * 64 + ms * 16 + r) * 40 + q * 8];
#pragma unroll
    for (int ns = 0; ns < 2; ns++)
      bfr[ns] = *(bf16x8*)&Bs[(wn * 32 + ns * 16 + r) * 40 + q * 8];
#pragma unroll
    for (int ms = 0; ms < 4; ms++)
#pragma unroll
      for (int ns = 0; ns < 2; ns++)
        acc[ms][ns] = mfma16(af[ms], bfr[ns], acc[ms][ns]);
    __syncthreads();
  }
#pragma unroll
  for (int ns = 0; ns < 2; ns++) {
    int col = nbase + wn * 32 + ns * 16 + r;
    float bias = b2[col];
#pragma unroll
    for (int ms = 0; ms < 4; ms++) {
      int row0 = mbase + wm * 64 + ms * 16 + q * 4;
      bf16x4 pk;
#pragma unroll
      for (int reg = 0; reg < 4; reg++) {
        float v = acc[ms][ns][reg] + bias;
        hb[(size_t)(row0 + reg) * ODIM + col] = (bf16_t)v;
        pk[reg] = (bf16_t)v;
      }
      *(bf16x4*)(hT + (size_t)col * NROWS + row0) = pk;
    }
  }
}

// ---------------------------------------------------------------------------
// flash (split-K, DMA-pipelined): grid = 128 qtiles x KS. Block = 4 waves,
// each wave owns 32 q-rows. Staging via global_load_lds into fragment-ordered
// 1KB LDS blocks; KT double-buffered so next-iter DMA overlaps softmax+O.
// ---------------------------------------------------------------------------
__global__ __launch_bounds__(256, 4) void flash(const bf16_t* __restrict__ hb,
                                                const bf16_t* __restrict__ hT,
                                                bf16_t* __restrict__ OpA,
                                                bf16_t* __restrict__ OpB,
                                                float* __restrict__ Ml) {
  __shared__ __align__(16) u16 KA[8 * 512];       // 8 frag blocks of 1KB
  __shared__ __align__(16) u16 KT[2][8 * 512];    // double-buffered
  __shared__ __align__(16) u16 Pm[4 * 32 * 40];   // per-wave P [qr][kr]

  int tid = threadIdx.x;
  int lane = tid & 63, w = tid >> 6;
  int r = lane & 15, q = lane >> 4;
  int ksplit = blockIdx.x >> 7;
  int qtile = blockIdx.x & 127;
  int qbase = qtile * 128 + w * 32;
  int kbase = ksplit * (NROWS / KS);
  const int niter = (NROWS / KS) / 32;  // 64

  // staging: waves 0,1 -> KA blocks (mt=w, kk=j); waves 2,3 -> KT blocks m8=(w-2)*4+j
  const char* gbase;
  size_t jmul;
  int ginc;
  u16* dbase;
  if (w < 2) {
    gbase = (const char*)(hb + (size_t)(kbase + w * 16 + r) * ODIM + q * 8);
    jmul = 32 * 2;            // kk stride: 32 shorts
    ginc = 32 * ODIM * 2;     // next 32-k chunk
    dbase = KA + w * 4 * 512;
  } else {
    gbase = (const char*)(hT + (size_t)((w - 2) * 64 + r) * NROWS + kbase + q * 8);
    jmul = (size_t)16 * NROWS * 2;  // m8 stride: 16 rows
    ginc = 32 * 2;                  // next 32-k chunk
    dbase = KT[0] + (w - 2) * 4 * 512;
  }

  // Q fragments resident in registers
  bf16x8 qf[2][4];
#pragma unroll
  for (int qt = 0; qt < 2; qt++) {
    int qrow = qbase + qt * 16 + r;
#pragma unroll
    for (int kk = 0; kk < 4; kk++)
      qf[qt][kk] = *(const bf16x8*)(hb + (size_t)qrow * ODIM + kk * 32 + q * 8);
  }

  f32x4 oa[8][2];
#pragma unroll
  for (int m8 = 0; m8 < 8; m8++)
#pragma unroll
    for (int qt = 0; qt < 2; qt++) oa[m8][qt] = (f32x4){0.f, 0.f, 0.f, 0.f};
  float m_run[2] = {0.f, 0.f}, l_run[2] = {0.f, 0.f};

  // issue iter-0 DMAs (KT -> buffer 0)
#pragma unroll
  for (int j = 0; j < 4; j++) dma16(gbase + j * jmul, dbase + j * 512);
  gbase += ginc;

  for (int it = 0; it < niter; it++) {
    __syncthreads();  // drains vmcnt -> KA(it), KT(it) ready

    // ---- S^T = K_chunk . Q^T ----
    f32x4 s[2][2];
#pragma unroll
    for (int mt = 0; mt < 2; mt++)
#pragma unroll
      for (int qt = 0; qt < 2; qt++) s[mt][qt] = (f32x4){0.f, 0.f, 0.f, 0.f};
#pragma unroll
    for (int mt = 0; mt < 2; mt++)
#pragma unroll
      for (int kk = 0; kk < 4; kk++) {
        bf16x8 af = *(bf16x8*)&KA[(mt * 4 + kk) * 512 + lane * 8];
        s[mt][0] = mfma16(af, qf[0][kk], s[mt][0]);
        s[mt][1] = mfma16(af, qf[1][kk], s[mt][1]);
      }
    __syncthreads();  // all waves done reading KA

    // ---- prefetch next chunk (KA single-buf now free; KT -> other buffer) ----
    if (it + 1 < niter) {
      u16* d = dbase;
      if (w >= 2) d += ((it + 1) & 1) * 4096;
#pragma unroll
      for (int j = 0; j < 4; j++) dma16(gbase + j * jmul, d + j * 512);
      gbase += ginc;
    }

    // ---- masked online softmax ----
    float mx[2];
#pragma unroll
    for (int qt = 0; qt < 2; qt++) {
      float m = m_run[qt];
#pragma unroll
      for (int mt = 0; mt < 2; mt++)
#pragma unroll
        for (int reg = 0; reg < 4; reg++) {
          float v = s[mt][qt][reg];
          m = v > 0.f ? fmaxf(m, v) : m;
        }
      m = fmaxf(m, __shfl_xor(m, 16, 64));
      m = fmaxf(m, __shfl_xor(m, 32, 64));
      mx[qt] = m;
    }
    if (__any(mx[0] > m_run[0] || mx[1] > m_run[1])) {
      float sc0 = __expf(m_run[0] - mx[0]);
      float sc1 = __expf(m_run[1] - mx[1]);
      m_run[0] = mx[0]; m_run[1] = mx[1];
      l_run[0] *= sc0; l_run[1] *= sc1;
#pragma unroll
      for (int m8 = 0; m8 < 8; m8++)
#pragma unroll
        for (int reg = 0; reg < 4; reg++) {
          oa[m8][0][reg] *= sc0;
          oa[m8][1][reg] *= sc1;
        }
    }
#pragma unroll
    for (int qt = 0; qt < 2; qt++) {
      float rs = 0.f;
      bf16x4 pk[2];
#pragma unroll
      for (int mt = 0; mt < 2; mt++)
#pragma unroll
        for (int reg = 0; reg < 4; reg++) {
          float v = s[mt][qt][reg];
          float p = v > 0.f ? __expf(v - m_run[qt]) : 0.f;
          rs += p;
          pk[mt][reg] = (bf16_t)p;
        }
      rs += __shfl_xor(rs, 16, 64);
      rs += __shfl_xor(rs, 32, 64);
      l_run[qt] += rs;
#pragma unroll
      for (int mt = 0; mt < 2; mt++)
        *(bf16x4*)&Pm[w * 1280 + (qt * 16 + r) * 40 + mt * 16 + q * 4] = pk[mt];
    }

    // ---- O^T += K^T . P^T ----
    bf16x8 pf0 = *(bf16x8*)&Pm[w * 1280 + r * 40 + q * 8];
    bf16x8 pf1 = *(bf16x8*)&Pm[w * 1280 + (16 + r) * 40 + q * 8];
    const u16* kt = KT[it & 1];
#pragma unroll
    for (int m8 = 0; m8 < 8; m8++) {
      bf16x8 af = *(bf16x8*)&kt[m8 * 512 + lane * 8];
      oa[m8][0] = mfma16(af, pf0, oa[m8][0]);
      oa[m8][1] = mfma16(af, pf1, oa[m8][1]);
    }
  }

  // ---- write partials ----
  bf16_t* op = ksplit < 6 ? OpA + (size_t)ksplit * NROWS * ODIM
                          : OpB + (size_t)(ksplit - 6) * NROWS * ODIM;
#pragma unroll
  for (int qt = 0; qt < 2; qt++) {
    int row = qbase + qt * 16 + r;
#pragma unroll
    for (int m8 = 0; m8 < 8; m8++) {
      bf16x4 pk;
#pragma unroll
      for (int reg = 0; reg < 4; reg++) pk[reg] = (bf16_t)oa[m8][qt][reg];
      *(bf16x4*)(op + (size_t)row * ODIM + m8 * 16 + q * 4) = pk;
    }
    if (q == 0) {
      Ml[(ksplit * NROWS + row) * 2 + 0] = m_run[qt];
      Ml[(ksplit * NROWS + row) * 2 + 1] = l_run[qt];
    }
  }
}

// ---------------------------------------------------------------------------
// merge: combine KS partials, apply alpha/beta/h, log_softmax, write out.
// ---------------------------------------------------------------------------
__global__ __launch_bounds__(256) void merge_ls(const bf16_t* __restrict__ OpA,
                                                const bf16_t* __restrict__ OpB,
                                                const float* __restrict__ Ml,
                                                const bf16_t* __restrict__ hbf,
                                                const float* __restrict__ alpha_p,
                                                const float* __restrict__ beta_p,
                                                float* __restrict__ out) {
  int tid = threadIdx.x, lane = tid & 63, w = tid >> 6;
  float al = alpha_p[0], be = beta_p[0];
  for (int i = 0; i < 8; i++) {
    int row = blockIdx.x * 32 + w * 8 + i;
    float mk[KS], lk[KS], ak[KS];
    float M = 0.f;
#pragma unroll
    for (int ksp = 0; ksp < KS; ksp++) {
      mk[ksp] = Ml[(ksp * NROWS + row) * 2 + 0];
      lk[ksp] = Ml[(ksp * NROWS + row) * 2 + 1];
      M = fmaxf(M, mk[ksp]);
    }
    float lt = 0.f;
#pragma unroll
    for (int ksp = 0; ksp < KS; ksp++) {
      ak[ksp] = __expf(mk[ksp] - M);
      lt += lk[ksp] * ak[ksp];
    }
    float inv = al / lt;
    int d0 = lane * 2;
    float a0 = 0.f, a1 = 0.f;
#pragma unroll
    for (int ksp = 0; ksp < KS; ksp++) {
      const bf16_t* op = ksp < 6 ? OpA + (size_t)ksp * NROWS * ODIM
                                 : OpB + (size_t)(ksp - 6) * NROWS * ODIM;
      bf16x2 v = *(const bf16x2*)(op + (size_t)row * ODIM + d0);
      a0 += ak[ksp] * (float)v[0];
      a1 += ak[ksp] * (float)v[1];
    }
    bf16x2 hv = *(const bf16x2*)(hbf + (size_t)row * ODIM + d0);
    float v0 = inv * a0 + be * (float)hv[0];
    float v1 = inv * a1 + be * (float)hv[1];
    float mxv = fmaxf(v0, v1);
#pragma unroll
    for (int off = 1; off < 64; off <<= 1) mxv = fmaxf(mxv, __shfl_xor(mxv, off, 64));
    float se = __expf(v0 - mxv) + __expf(v1 - mxv);
#pragma unroll
    for (int off = 1; off < 64; off <<= 1) se += __shfl_xor(se, off, 64);
    float lz = mxv + __logf(se);
    f32x2 st = {v0 - lz, v1 - lz};
    *(f32x2*)(out + (size_t)row * ODIM + d0) = st;
  }
}

// ---------------------------------------------------------------------------
extern "C" void kernel_launch(void* const* d_in, const int* in_sizes, int n_in,
                              void* d_out, int out_size, void* d_ws,
                              size_t ws_size, hipStream_t stream) {
  const float* x     = (const float*)d_in[0];
  const float* W1    = (const float*)d_in[2];
  const float* b1    = (const float*)d_in[3];
  const float* W2    = (const float*)d_in[4];
  const float* b2    = (const float*)d_in[5];
  const float* alpha = (const float*)d_in[6];
  const float* beta  = (const float*)d_in[7];

  char* ws = (char*)d_ws;
  // [0, 25493504): xb(16M) + W1T(256K) + W2T(64K) + h1(8M) — all dead during
  // flash/merge, reused as Op splits 0..5 (24MB).
  bf16_t* xb  = (bf16_t*)(ws + 0);
  bf16_t* W1T = (bf16_t*)(ws + 16777216);
  bf16_t* W2T = (bf16_t*)(ws + 17039360);
  bf16_t* h1  = (bf16_t*)(ws + 17104896);   // ends 25493504
  bf16_t* hbf = (bf16_t*)(ws + 25493504);   // 4MB
  bf16_t* hT  = (bf16_t*)(ws + 29687808);   // 4MB
  float*  Ml  = (float*)(ws + 33882112);    // 1MB
  bf16_t* OpB = (bf16_t*)(ws + 34930688);   // 2 x 4MB -> total 43.3MB
  bf16_t* OpA = (bf16_t*)(ws + 0);          // overlays xb/W1T/W2T/h1
  float* outp = (float*)d_out;

  prep<<<1024, 256, 0, stream>>>(x, W1, W2, xb, W1T, W2T);
  gemm1<<<dim3(128, 4), 256, 0, stream>>>(xb, W1T, b1, h1);
  gemm2<<<dim3(128, 2), 256, 0, stream>>>(h1, W2T, b2, hbf, hT);
  flash<<<128 * KS, 256, 0, stream>>>(hbf, hT, OpA, OpB, Ml);
  merge_ls<<<512, 256, 0, stream>>>(OpA, OpB, Ml, hbf, alpha, beta, outp);
}